// Round 3
// baseline (3140.787 us; speedup 1.0000x reference)
//
#include <hip/hip_runtime.h>
#include <stdint.h>

#define GRID_Z 10
#define GRID_Y 400
#define GRID_X 352
#define NGRID (GRID_Z * GRID_Y * GRID_X)   // 1,408,000
#define NVOX 200000
#define CCH 128
#define MROI 64
#define GXD 64
#define GYD 32
#define GZD 4
#define GCELLS 8192                         // GXD*GYD*GZD
#define NTAPS 147                           // 7*7*3

// Recompute a grid cell's world xyz exactly like the reference (fp32, no fma
// contraction so floor() boundaries match XLA's mul+add evaluation).
__device__ __forceinline__ void cell_xyz(const float* __restrict__ roi, int g,
                                         float& X, float& Y, float& Z) {
#pragma clang fp contract(off)
    int iz = g & 3;
    int iy = (g >> 2) & 31;
    int ix = g >> 7;
    float bx = roi[3] * 2.0f;   // EXTEND on x,y dims
    float by = roi[4] * 2.0f;
    float bz = roi[5];
    float lx = (ix + 0.5f) / 64.0f * bx - bx / 2.0f;
    float ly = (iy + 0.5f) / 32.0f * by - by / 2.0f;
    float lz = (iz + 0.5f) / 4.0f  * bz - bz / 2.0f;
    float c = cosf(roi[6]);
    float s = sinf(roi[6]);
    X = lx * c + ly * (-s) + roi[0];
    Y = lx * s + ly * c    + roi[1];
    Z = lz + roi[2];
}

__global__ void k_init(int* __restrict__ v2p, unsigned long long* __restrict__ best) {
    int i = blockIdx.x * 256 + threadIdx.x;   // grid sized to exactly NGRID
    v2p[i] = -1;
    if (i < MROI) best[i] = 0ull;
}

__global__ void k_scatter(const int* __restrict__ vcoords, int* __restrict__ v2p) {
    int i = blockIdx.x * 256 + threadIdx.x;
    if (i >= NVOX) return;
    int z = vcoords[i * 4 + 1];
    int y = vcoords[i * 4 + 2];
    int x = vcoords[i * 4 + 3];
    // Duplicate coords: XLA scatter applies updates in order -> last (max idx) wins.
    atomicMax(&v2p[(z * GRID_Y + y) * GRID_X + x], i);
}

__global__ void k_pidx(const float* __restrict__ rois, const int* __restrict__ v2p,
                       int* __restrict__ pidx) {
#pragma clang fp contract(off)
    int g = blockIdx.x * 256 + threadIdx.x;   // [0, GCELLS)
    int m = blockIdx.y;
    const float* roi = rois + m * 7;
    float X, Y, Z;
    cell_xyz(roi, g, X, Y, Z);
    float fx = floorf((X - 0.0f)     / 0.05f);
    float fy = floorf((Y - (-40.0f)) / 0.05f);
    float fz = floorf((Z - (-3.0f))  / 0.1f);
    int cx = (int)floorf(fx / 4.0f);
    int cy = (int)floorf(fy / 4.0f);
    int cz = (int)floorf(fz / 4.0f);
    int p = -1;
    if (cz >= 0 && cz < GRID_Z && cy >= 0 && cy < GRID_Y && cx >= 0 && cx < GRID_X)
        p = v2p[(cz * GRID_Y + cy) * GRID_X + cx];
    pidx[m * GCELLS + g] = p;
}

// One half-wave (32 lanes) per output cell, lane covers 4 channels (float4).
// Proto stays in L1/L2 (read-only, 75 KB, shared by all blocks) -- NO LDS
// staging, NO barriers. Phase 1 ballot-compacts valid (p,k) taps into a small
// LDS list; phase 2 walks it 4 taps at a time (8 global loads in flight).
__global__ __launch_bounds__(256) void k_score(
        const float* __restrict__ vfeat, const float* __restrict__ fproto,
        const int* __restrict__ pidx, unsigned long long* __restrict__ best) {
    __shared__ unsigned slist[8][NTAPS + 13];  // per-cell compact tap list, 5 KB

    int tid  = threadIdx.x;
    int lane = tid & 63;
    int wave = tid >> 6;
    int half = lane >> 5;
    int l32  = lane & 31;
    int slot = wave * 2 + half;               // 0..7: which cell of this block
    int cell = blockIdx.x * 8 + slot;         // [0, MROI*GCELLS)
    int m = cell >> 13;
    int g = cell & (GCELLS - 1);
    int gx = g >> 7;
    int gy = (g >> 2) & 31;
    int gz = g & 3;
    const int*    pid = pidx + m * GCELLS;
    const float4* vf4 = (const float4*)vfeat;
    const float4* pf4 = (const float4*)fproto;

    // ---- Phase 1: parallel validity + ballot compaction (5 rounds) ----
    int cnt = 0;                              // half-wave-uniform register
    #pragma unroll
    for (int r = 0; r < 5; ++r) {
        int t = r * 32 + l32;                 // tap id [0,160); >=147 invalid
        int p = -1;
        if (t < NTAPS) {
            int kx  = t / 21;
            int rem = t - kx * 21;
            int ky  = rem / 3;
            int kz  = rem - ky * 3;
            int nx = gx + kx - 3;
            int ny = gy + ky - 3;
            int nz = gz + kz - 1;
            if ((unsigned)nx < (unsigned)GXD && (unsigned)ny < (unsigned)GYD &&
                (unsigned)nz < (unsigned)GZD)
                p = pid[(nx * GYD + ny) * GZD + nz];
        }
        bool v = p >= 0;
        unsigned long long bal = __ballot(v);
        unsigned bm = (unsigned)(bal >> (half * 32));
        if (v) {
            int pos = __popc(bm & ((1u << l32) - 1u));
            slist[slot][cnt + pos] = ((unsigned)p << 8) | (unsigned)t;
        }
        cnt += __popc(bm);
    }
    // sentinel pad so the 4-wide reads below never index garbage
    if (l32 < 4) slist[slot][cnt + l32] = 0u;

    // ---- Phase 2: 4 taps per iteration; feat + proto both from cache ----
    float4 acc = make_float4(0.f, 0.f, 0.f, 0.f);
    for (int i = 0; i < cnt; i += 4) {
        uint4 e = *(const uint4*)&slist[slot][i];   // broadcast b128
        unsigned ev0 = e.x, ev1 = e.y, ev2 = e.z, ev3 = e.w;
        #pragma unroll
        for (int j = 0; j < 4; ++j) {
            unsigned en = (j == 0) ? ev0 : (j == 1) ? ev1 : (j == 2) ? ev2 : ev3;
            int p = (int)(en >> 8);
            int t = (int)(en & 255u);
            float4 f = vf4[(size_t)p * (CCH / 4) + l32];
            float4 w = pf4[t * (CCH / 4) + l32];
            float msk = (i + j < cnt) ? 1.0f : 0.0f;
            acc.x += f.x * w.x * msk;
            acc.y += f.y * w.y * msk;
            acc.z += f.z * w.z * msk;
            acc.w += f.w * w.w * msk;
        }
    }

    // reduce across the half-wave (lane 0 / lane 32 end up with the two sums)
    float s = acc.x + acc.y + acc.z + acc.w;
    #pragma unroll
    for (int off = 16; off > 0; off >>= 1) s += __shfl_down(s, off, 64);

    if (l32 == 0) {
        unsigned ub  = __float_as_uint(s);
        unsigned key = (ub & 0x80000000u) ? ~ub : (ub | 0x80000000u);  // order-preserving
        unsigned long long packed =
            ((unsigned long long)key << 32) | (unsigned)(GCELLS - 1 - g);  // ties -> smallest g
        atomicMax(best + m, packed);
    }
}

__global__ void k_final(const float* __restrict__ rois, const float* __restrict__ pbox,
                        const unsigned long long* __restrict__ best,
                        float* __restrict__ out) {
    int m = threadIdx.x;
    if (m >= MROI) return;
    unsigned long long p = best[m];
    int g = (GCELLS - 1) - (int)(unsigned)(p & 0xFFFFFFFFu);
    float X, Y, Z;
    cell_xyz(rois + m * 7, g, X, Y, Z);
    out[m * 7 + 0] = X;
    out[m * 7 + 1] = Y;
    out[m * 7 + 2] = Z;
    out[m * 7 + 3] = pbox[3];
    out[m * 7 + 4] = pbox[4];
    out[m * 7 + 5] = pbox[5];
    out[m * 7 + 6] = pbox[6];
}

extern "C" void kernel_launch(void* const* d_in, const int* in_sizes, int n_in,
                              void* d_out, int out_size, void* d_ws, size_t ws_size,
                              hipStream_t stream) {
    const float* rois    = (const float*)d_in[0];
    const float* pbox    = (const float*)d_in[1];
    const float* vfeat   = (const float*)d_in[2];
    const float* fproto  = (const float*)d_in[3];
    const int*   vcoords = (const int*)d_in[4];
    float* out = (float*)d_out;

    int* v2p  = (int*)d_ws;                       // NGRID ints          (5.63 MB)
    int* pidx = v2p + NGRID;                      // MROI*GCELLS ints    (2.10 MB)
    unsigned long long* best =
        (unsigned long long*)(pidx + MROI * GCELLS);  // 64 x u64 (8B-aligned)

    k_init   <<<NGRID / 256, 256, 0, stream>>>(v2p, best);
    k_scatter<<<(NVOX + 255) / 256, 256, 0, stream>>>(vcoords, v2p);
    k_pidx   <<<dim3(GCELLS / 256, MROI), 256, 0, stream>>>(rois, v2p, pidx);
    k_score  <<<MROI * GCELLS / 8, 256, 0, stream>>>(vfeat, fproto, pidx, best);
    k_final  <<<1, 64, 0, stream>>>(rois, pbox, best, out);
}

// Round 4
// 456.487 us; speedup vs baseline: 6.8803x; 6.8803x over previous
//
#include <hip/hip_runtime.h>
#include <stdint.h>

#define GRID_Z 10
#define GRID_Y 400
#define GRID_X 352
#define NGRID (GRID_Z * GRID_Y * GRID_X)   // 1,408,000
#define NVOX 200000
#define CCH 128
#define MROI 64
#define GXD 64
#define GYD 32
#define GZD 4
#define GCELLS 8192                         // GXD*GYD*GZD
#define NTAPS 147                           // 7*7*3

// Recompute a grid cell's world xyz exactly like the reference (fp32, no fma
// contraction so floor() boundaries match XLA's mul+add evaluation).
__device__ __forceinline__ void cell_xyz(const float* __restrict__ roi, int g,
                                         float& X, float& Y, float& Z) {
#pragma clang fp contract(off)
    int iz = g & 3;
    int iy = (g >> 2) & 31;
    int ix = g >> 7;
    float bx = roi[3] * 2.0f;   // EXTEND on x,y dims
    float by = roi[4] * 2.0f;
    float bz = roi[5];
    float lx = (ix + 0.5f) / 64.0f * bx - bx / 2.0f;
    float ly = (iy + 0.5f) / 32.0f * by - by / 2.0f;
    float lz = (iz + 0.5f) / 4.0f  * bz - bz / 2.0f;
    float c = cosf(roi[6]);
    float s = sinf(roi[6]);
    X = lx * c + ly * (-s) + roi[0];
    Y = lx * s + ly * c    + roi[1];
    Z = lz + roi[2];
}

// DPP xor-add helper (VALU pipe, not DS). CTRL: 0xB1=xor1, 0x4E=xor2,
// 0x141=row_half_mirror (xor7), 0x140=row_mirror (xor15).
template <int CTRL>
__device__ __forceinline__ float xadd(float v) {
    int mv = __builtin_amdgcn_update_dpp(0, __float_as_int(v), CTRL, 0xF, 0xF, true);
    return v + __int_as_float(mv);
}
// 32-lane sum; result in ALL 32 lanes of each half-wave. Masks {1,2,7,15,16}
// generate the full group (each step doubles the subgroup -> valid butterfly).
__device__ __forceinline__ float red32(float v) {
    v = xadd<0xB1>(v);
    v = xadd<0x4E>(v);
    v = xadd<0x141>(v);
    v = xadd<0x140>(v);
    int s = __builtin_amdgcn_ds_swizzle(__float_as_int(v), 0x401F);  // xor16
    return v + __int_as_float(s);
}

__global__ void k_init(int* __restrict__ v2p, int* __restrict__ cnt,
                       unsigned long long* __restrict__ best) {
    int i = blockIdx.x * 256 + threadIdx.x;   // grid sized to exactly NGRID
    v2p[i] = -1;
    if (i < MROI) { cnt[i] = 0; best[i] = 0ull; }
}

__global__ void k_scatter(const int* __restrict__ vcoords, int* __restrict__ v2p) {
    int i = blockIdx.x * 256 + threadIdx.x;
    if (i >= NVOX) return;
    int z = vcoords[i * 4 + 1];
    int y = vcoords[i * 4 + 2];
    int x = vcoords[i * 4 + 3];
    // Duplicate coords: XLA scatter applies updates in order -> last (max idx) wins.
    atomicMax(&v2p[(z * GRID_Y + y) * GRID_X + x], i);
}

// Per (m, g): map grid cell to voxel index; ballot-compact valid (p,g) pairs
// into a per-ROI list. Order within list is nondeterministic (atomic) -- only
// affects fp summation order at ~1e-7, argmax stable off exact ties.
__global__ void k_build(const float* __restrict__ rois, const int* __restrict__ v2p,
                        unsigned* __restrict__ list, int* __restrict__ cnt) {
#pragma clang fp contract(off)
    int g = blockIdx.x * 256 + threadIdx.x;   // [0, GCELLS)
    int m = blockIdx.y;
    int lane = threadIdx.x & 63;
    const float* roi = rois + m * 7;
    float X, Y, Z;
    cell_xyz(roi, g, X, Y, Z);
    float fx = floorf((X - 0.0f)     / 0.05f);
    float fy = floorf((Y - (-40.0f)) / 0.05f);
    float fz = floorf((Z - (-3.0f))  / 0.1f);
    int cx = (int)floorf(fx / 4.0f);
    int cy = (int)floorf(fy / 4.0f);
    int cz = (int)floorf(fz / 4.0f);
    int p = -1;
    if (cz >= 0 && cz < GRID_Z && cy >= 0 && cy < GRID_Y && cx >= 0 && cx < GRID_X)
        p = v2p[(cz * GRID_Y + cy) * GRID_X + cx];
    bool v = p >= 0;
    unsigned long long bal = __ballot(v);
    int nset = __popcll(bal);
    int base = 0;
    if (lane == 0 && nset) base = atomicAdd(&cnt[m], nset);
    base = __shfl(base, 0, 64);
    if (v) {
        int pos = __popcll(bal & ((1ull << lane) - 1ull));
        list[m * GCELLS + base + pos] = ((unsigned)p << 13) | (unsigned)g;
    }
}

__global__ void k_zero(float* __restrict__ score) {
    score[blockIdx.x * 256 + threadIdx.x] = 0.0f;   // grid = MROI*GCELLS/256
}

// One half-wave per voxel (lane = 4 channels, float4 in regs). For each of the
// 147 taps: proto row from L1/L2, dot, DPP butterfly reduce, deposit the sum
// in lane (t&31); after each 32-tap round, scatter-add 32 dots to the cells
// they serve (cell = voxelpos - tap offset) via global atomicAdd.
__global__ __launch_bounds__(256) void k_dots(
        const float* __restrict__ vfeat, const float* __restrict__ fproto,
        const unsigned* __restrict__ list, const int* __restrict__ cnt,
        float* __restrict__ score) {
    int m    = blockIdx.y;
    int tid  = threadIdx.x;
    int lane = tid & 63;
    int l32  = lane & 31;
    int hw   = (tid >> 6) * 2 + (lane >> 5);   // 0..7 half-wave id
    int n = cnt[m];
    const float4* vf4 = (const float4*)vfeat;
    const float4* pf4 = (const float4*)fproto;
    const unsigned* lst = list + m * GCELLS;
    float* sc = score + m * GCELLS;

    for (int vi = blockIdx.x * 8 + hw; vi < n; vi += 32 * 8) {
        unsigned e = lst[vi];                  // half-wave-uniform broadcast
        int p  = (int)(e >> 13);
        int g  = (int)(e & 8191u);
        int gx = g >> 7, gy = (g >> 2) & 31, gz = g & 3;
        float4 f = vf4[(size_t)p * (CCH / 4) + l32];

        #pragma unroll
        for (int r = 0; r < 5; ++r) {
            int nt = (r == 4) ? (NTAPS - 128) : 32;   // last round: 19 taps
            int t0 = r * 32;
            float sacc = 0.0f;
            #pragma unroll 4
            for (int j = 0; j < nt; ++j) {
                float4 w = pf4[(t0 + j) * (CCH / 4) + l32];
                float d = fmaf(f.x, w.x, fmaf(f.y, w.y, fmaf(f.z, w.z, f.w * w.w)));
                d = red32(d);
                sacc = (l32 == j) ? d : sacc;
            }
            int t = t0 + l32;
            if (l32 < nt) {
                int kx = t / 21;
                int rem = t - kx * 21;
                int ky = rem / 3;
                int kz = rem - ky * 3;
                int cx = gx - (kx - 3);
                int cy = gy - (ky - 3);
                int cz = gz - (kz - 1);
                if ((unsigned)cx < (unsigned)GXD && (unsigned)cy < (unsigned)GYD &&
                    (unsigned)cz < (unsigned)GZD)
                    atomicAdd(sc + ((cx << 7) | (cy << 2) | cz), sacc);
            }
        }
    }
}

__global__ void k_argmax(const float* __restrict__ score,
                         unsigned long long* __restrict__ best) {
    int m = blockIdx.x;
    int tid = threadIdx.x;
    const float* sc = score + m * GCELLS;
    unsigned long long bk = 0ull;
    for (int g = tid; g < GCELLS; g += 256) {
        float v = sc[g];
        unsigned ub  = __float_as_uint(v);
        unsigned key = (ub & 0x80000000u) ? ~ub : (ub | 0x80000000u);  // order-preserving
        unsigned long long pk =
            ((unsigned long long)key << 32) | (unsigned)(GCELLS - 1 - g);  // ties -> smallest g
        bk = bk > pk ? bk : pk;
    }
    atomicMax(best + m, bk);
}

__global__ void k_final(const float* __restrict__ rois, const float* __restrict__ pbox,
                        const unsigned long long* __restrict__ best,
                        float* __restrict__ out) {
    int m = threadIdx.x;
    if (m >= MROI) return;
    unsigned long long p = best[m];
    int g = (GCELLS - 1) - (int)(unsigned)(p & 0xFFFFFFFFu);
    float X, Y, Z;
    cell_xyz(rois + m * 7, g, X, Y, Z);
    out[m * 7 + 0] = X;
    out[m * 7 + 1] = Y;
    out[m * 7 + 2] = Z;
    out[m * 7 + 3] = pbox[3];
    out[m * 7 + 4] = pbox[4];
    out[m * 7 + 5] = pbox[5];
    out[m * 7 + 6] = pbox[6];
}

extern "C" void kernel_launch(void* const* d_in, const int* in_sizes, int n_in,
                              void* d_out, int out_size, void* d_ws, size_t ws_size,
                              hipStream_t stream) {
    const float* rois    = (const float*)d_in[0];
    const float* pbox    = (const float*)d_in[1];
    const float* vfeat   = (const float*)d_in[2];
    const float* fproto  = (const float*)d_in[3];
    const int*   vcoords = (const int*)d_in[4];
    float* out = (float*)d_out;

    // ws layout (7.74 MB): best | v2p (aliased by score after k_build) | list | cnt
    unsigned long long* best = (unsigned long long*)d_ws;      // 64 u64
    int*      v2p   = (int*)(best + MROI);                     // NGRID ints
    float*    score = (float*)v2p;                             // aliases v2p (dead after k_build)
    unsigned* list  = (unsigned*)(v2p + NGRID);                // MROI*GCELLS
    int*      cnt   = (int*)(list + MROI * GCELLS);            // 64 ints

    k_init   <<<NGRID / 256, 256, 0, stream>>>(v2p, cnt, best);
    k_scatter<<<(NVOX + 255) / 256, 256, 0, stream>>>(vcoords, v2p);
    k_build  <<<dim3(GCELLS / 256, MROI), 256, 0, stream>>>(rois, v2p, list, cnt);
    k_zero   <<<MROI * GCELLS / 256, 256, 0, stream>>>(score);
    k_dots   <<<dim3(32, MROI), 256, 0, stream>>>(vfeat, fproto, list, cnt, score);
    k_argmax <<<MROI, 256, 0, stream>>>(score, best);
    k_final  <<<1, 64, 0, stream>>>(rois, pbox, best, out);
}

// Round 5
// 375.404 us; speedup vs baseline: 8.3664x; 1.2160x over previous
//
#include <hip/hip_runtime.h>
#include <stdint.h>

#define GRID_Z 10
#define GRID_Y 400
#define GRID_X 352
#define NGRID (GRID_Z * GRID_Y * GRID_X)   // 1,408,000
#define NVOX 200000
#define CCH 128
#define MROI 64
#define GXD 64
#define GYD 32
#define GZD 4
#define GCELLS 8192                         // GXD*GYD*GZD
#define NTAPS 147                           // 7*7*3
#define NBLKX 8                             // voxel-tile blocks per ROI
#define FPAD 132                            // feat LDS row pitch (128+4: bank-conflict-free, 16B-aligned)
#define SCORE_ELEMS (MROI * GCELLS)

// Recompute a grid cell's world xyz exactly like the reference (fp32, no fma
// contraction so floor() boundaries match XLA's mul+add evaluation).
__device__ __forceinline__ void cell_xyz(const float* __restrict__ roi, int g,
                                         float& X, float& Y, float& Z) {
#pragma clang fp contract(off)
    int iz = g & 3;
    int iy = (g >> 2) & 31;
    int ix = g >> 7;
    float bx = roi[3] * 2.0f;   // EXTEND on x,y dims
    float by = roi[4] * 2.0f;
    float bz = roi[5];
    float lx = (ix + 0.5f) / 64.0f * bx - bx / 2.0f;
    float ly = (iy + 0.5f) / 32.0f * by - by / 2.0f;
    float lz = (iz + 0.5f) / 4.0f  * bz - bz / 2.0f;
    float c = cosf(roi[6]);
    float s = sinf(roi[6]);
    X = lx * c + ly * (-s) + roi[0];
    Y = lx * s + ly * c    + roi[1];
    Z = lz + roi[2];
}

// init v2p=-1, cnt=0, and (fast path) zero the score grid in the same sweep.
__global__ void k_init(int* __restrict__ v2p, int* __restrict__ cnt,
                       float* __restrict__ score, int zero_score) {
    int i = blockIdx.x * 256 + threadIdx.x;   // grid sized to exactly NGRID
    v2p[i] = -1;
    if (zero_score && i < SCORE_ELEMS) score[i] = 0.0f;
    if (i < MROI) cnt[i] = 0;
}

__global__ void k_scatter(const int* __restrict__ vcoords, int* __restrict__ v2p) {
    int i = blockIdx.x * 256 + threadIdx.x;
    if (i >= NVOX) return;
    int z = vcoords[i * 4 + 1];
    int y = vcoords[i * 4 + 2];
    int x = vcoords[i * 4 + 3];
    // Duplicate coords: XLA scatter applies updates in order -> last (max idx) wins.
    atomicMax(&v2p[(z * GRID_Y + y) * GRID_X + x], i);
}

// Per (m, g): map grid cell to voxel index; ballot-compact valid (p,g) pairs
// into a per-ROI list (order nondeterministic; only perturbs fp sum order).
__global__ void k_build(const float* __restrict__ rois, const int* __restrict__ v2p,
                        unsigned* __restrict__ list, int* __restrict__ cnt) {
#pragma clang fp contract(off)
    int g = blockIdx.x * 256 + threadIdx.x;   // [0, GCELLS)
    int m = blockIdx.y;
    int lane = threadIdx.x & 63;
    const float* roi = rois + m * 7;
    float X, Y, Z;
    cell_xyz(roi, g, X, Y, Z);
    float fx = floorf((X - 0.0f)     / 0.05f);
    float fy = floorf((Y - (-40.0f)) / 0.05f);
    float fz = floorf((Z - (-3.0f))  / 0.1f);
    int cx = (int)floorf(fx / 4.0f);
    int cy = (int)floorf(fy / 4.0f);
    int cz = (int)floorf(fz / 4.0f);
    int p = -1;
    if (cz >= 0 && cz < GRID_Z && cy >= 0 && cy < GRID_Y && cx >= 0 && cx < GRID_X)
        p = v2p[(cz * GRID_Y + cy) * GRID_X + cx];
    bool v = p >= 0;
    unsigned long long bal = __ballot(v);
    int nset = __popcll(bal);
    int base = 0;
    if (lane == 0 && nset) base = atomicAdd(&cnt[m], nset);
    base = __shfl(base, 0, 64);
    if (v) {
        int pos = __popcll(bal & ((1ull << lane) - 1ull));
        list[m * GCELLS + base + pos] = ((unsigned)p << 13) | (unsigned)g;
    }
}

__global__ void k_zero(float* __restrict__ score) {
    score[blockIdx.x * 256 + threadIdx.x] = 0.0f;   // grid = SCORE_ELEMS/256
}

// Batched-GEMM dots + scatter. Block: 64-voxel tile staged in LDS; wave w owns
// taps [40w, 40w+40); lane (vi=l&7, ti=(l>>3)&7) computes an 8-voxel x 5-tap
// register tile over K=128 (4 ch/step). Proto rows come from L1 (20 KB sliding
// window); feat rows from LDS (padded pitch -> conflict-free ds_read_b128).
// Epilogue scatters each dot to its served cell via atomicAdd.
__global__ __launch_bounds__(256) void k_dots(
        const float* __restrict__ vfeat, const float* __restrict__ fproto,
        const unsigned* __restrict__ list, const int* __restrict__ cnt,
        float* __restrict__ score) {
    __shared__ float    sfeat[64 * FPAD];     // 33.8 KB
    __shared__ unsigned sg[64];

    const int m    = blockIdx.y;
    const int tid  = threadIdx.x;
    const int w    = tid >> 6;                // wave 0..3
    const int lane = tid & 63;
    const int vi   = lane & 7;
    const int ti   = (lane >> 3) & 7;
    const int n    = cnt[m];
    const unsigned* lst = list + m * GCELLS;
    float* sc = score + (size_t)m * GCELLS;
    const int tbase = w * 40 + ti;            // thread's taps: tbase + 8b, b=0..4

    for (int vt0 = blockIdx.x * 64; vt0 < n; vt0 += 64 * NBLKX) {
        __syncthreads();                      // prior tile's epilogue done
        {   // stage 64 feat rows + packed (p,g) entries
            int r = tid >> 2;                 // row 0..63
            int q = tid & 3;                  // 32-float quarter
            int v = vt0 + r;
            unsigned e = 0xFFFFFFFFu;
            if (v < n) e = lst[v];
            if (q == 0) sg[r] = e;
            if (e != 0xFFFFFFFFu) {
                int p = (int)(e >> 13);
                const float4* src = (const float4*)(vfeat + (size_t)p * CCH) + q * 8;
                float4* drow = (float4*)(sfeat + r * FPAD + q * 32);
                #pragma unroll
                for (int j = 0; j < 8; ++j) drow[j] = src[j];
            }
        }
        __syncthreads();

        float acc[8][5];
        #pragma unroll
        for (int a = 0; a < 8; ++a)
            #pragma unroll
            for (int b = 0; b < 5; ++b) acc[a][b] = 0.0f;

        #pragma unroll 1
        for (int k = 0; k < CCH; k += 4) {
            float4 f[8];
            #pragma unroll
            for (int a = 0; a < 8; ++a)
                f[a] = *(const float4*)&sfeat[(vi + 8 * a) * FPAD + k];
            float4 wv[5];
            #pragma unroll
            for (int b = 0; b < 5; ++b) {
                int t = tbase + 8 * b;
                int tc = t > (NTAPS - 1) ? (NTAPS - 1) : t;   // clamp: no OOB read
                wv[b] = *(const float4*)(fproto + tc * CCH + k);
            }
            #pragma unroll
            for (int a = 0; a < 8; ++a)
                #pragma unroll
                for (int b = 0; b < 5; ++b) {
                    acc[a][b] = fmaf(f[a].x, wv[b].x, acc[a][b]);
                    acc[a][b] = fmaf(f[a].y, wv[b].y, acc[a][b]);
                    acc[a][b] = fmaf(f[a].z, wv[b].z, acc[a][b]);
                    acc[a][b] = fmaf(f[a].w, wv[b].w, acc[a][b]);
                }
        }

        // epilogue: scatter dots to the cells they serve
        #pragma unroll
        for (int b = 0; b < 5; ++b) {
            int t = tbase + 8 * b;
            if (t >= NTAPS) continue;
            int kx  = t / 21;
            int rem = t - kx * 21;
            int ky  = rem / 3;
            int kz  = rem - ky * 3;
            #pragma unroll
            for (int a = 0; a < 8; ++a) {
                unsigned e = sg[vi + 8 * a];
                if (e == 0xFFFFFFFFu) continue;
                int g  = (int)(e & 8191u);
                int cx = (g >> 7)        - (kx - 3);
                int cy = ((g >> 2) & 31) - (ky - 3);
                int cz = (g & 3)         - (kz - 1);
                if ((unsigned)cx < (unsigned)GXD && (unsigned)cy < (unsigned)GYD &&
                    (unsigned)cz < (unsigned)GZD)
                    atomicAdd(sc + ((cx << 7) | (cy << 2) | cz), acc[a][b]);
            }
        }
    }
}

// Fused argmax + output write: one block per ROI, no atomics, no best buffer.
__global__ void k_argfin(const float* __restrict__ score,
                         const float* __restrict__ rois,
                         const float* __restrict__ pbox,
                         float* __restrict__ out) {
    __shared__ unsigned long long red[256];
    int m = blockIdx.x;
    int tid = threadIdx.x;
    const float* sc = score + (size_t)m * GCELLS;
    unsigned long long bk = 0ull;
    for (int g = tid; g < GCELLS; g += 256) {
        float v = sc[g];
        unsigned ub  = __float_as_uint(v);
        unsigned key = (ub & 0x80000000u) ? ~ub : (ub | 0x80000000u);  // order-preserving
        unsigned long long pk =
            ((unsigned long long)key << 32) | (unsigned)(GCELLS - 1 - g);  // ties -> smallest g
        bk = bk > pk ? bk : pk;
    }
    red[tid] = bk;
    __syncthreads();
    for (int s = 128; s > 0; s >>= 1) {
        if (tid < s) {
            unsigned long long o = red[tid + s];
            if (o > red[tid]) red[tid] = o;
        }
        __syncthreads();
    }
    if (tid == 0) {
        int g = (GCELLS - 1) - (int)(unsigned)(red[0] & 0xFFFFFFFFu);
        float X, Y, Z;
        cell_xyz(rois + m * 7, g, X, Y, Z);
        out[m * 7 + 0] = X;
        out[m * 7 + 1] = Y;
        out[m * 7 + 2] = Z;
        out[m * 7 + 3] = pbox[3];
        out[m * 7 + 4] = pbox[4];
        out[m * 7 + 5] = pbox[5];
        out[m * 7 + 6] = pbox[6];
    }
}

extern "C" void kernel_launch(void* const* d_in, const int* in_sizes, int n_in,
                              void* d_out, int out_size, void* d_ws, size_t ws_size,
                              hipStream_t stream) {
    const float* rois    = (const float*)d_in[0];
    const float* pbox    = (const float*)d_in[1];
    const float* vfeat   = (const float*)d_in[2];
    const float* fproto  = (const float*)d_in[3];
    const int*   vcoords = (const int*)d_in[4];
    float* out = (float*)d_out;

    // ws layout: v2p | list | cnt | [score if room]  (score aliases v2p otherwise)
    int*      v2p  = (int*)d_ws;                               // NGRID ints (5.63 MB)
    unsigned* list = (unsigned*)(v2p + NGRID);                 // MROI*GCELLS (2.10 MB)
    int*      cnt  = (int*)(list + MROI * GCELLS);             // 64 ints
    size_t    used = (size_t)NGRID * 4 + (size_t)MROI * GCELLS * 4 + 256;
    bool   separate = (ws_size >= used + (size_t)SCORE_ELEMS * 4);
    float*    score = separate ? (float*)((char*)d_ws + used)  // own 2 MB region
                               : (float*)v2p;                  // alias (dead after k_build)

    k_init   <<<NGRID / 256, 256, 0, stream>>>(v2p, cnt, score, separate ? 1 : 0);
    k_scatter<<<(NVOX + 255) / 256, 256, 0, stream>>>(vcoords, v2p);
    k_build  <<<dim3(GCELLS / 256, MROI), 256, 0, stream>>>(rois, v2p, list, cnt);
    if (!separate)
        k_zero <<<SCORE_ELEMS / 256, 256, 0, stream>>>(score);
    k_dots   <<<dim3(NBLKX, MROI), 256, 0, stream>>>(vfeat, fproto, list, cnt, score);
    k_argfin <<<MROI, 256, 0, stream>>>(score, rois, pbox, out);
}